// Round 2
// baseline (13031.206 us; speedup 1.0000x reference)
//
#include <hip/hip_runtime.h>

#define NB 256
#define NM 128
#define ND 64
#define NH 8
#define STR 68   // f32 row stride for 64-wide LDS tiles (float4-aligned, breaks pow2 bank strides)

// One head's projection: dst[m][col] = sum_d xs[m][d] * W[d][h*64+col] + bias
// Partition: col = tid&63, rg = tid>>6 owns rows rg*16..rg*16+15.
// xs reads are wave-uniform (broadcast, conflict-free); W reads coalesced (64x4B).
__device__ __forceinline__ void proj_head(const float* __restrict__ Wg, float bias,
                                          const float* __restrict__ xs,
                                          float* __restrict__ dst, int rg, int col)
{
    float acc[16];
#pragma unroll
    for (int r = 0; r < 16; ++r) acc[r] = 0.f;
#pragma unroll
    for (int d4 = 0; d4 < 16; ++d4) {
        const float w0 = Wg[(4 * d4 + 0) * 512];
        const float w1 = Wg[(4 * d4 + 1) * 512];
        const float w2 = Wg[(4 * d4 + 2) * 512];
        const float w3 = Wg[(4 * d4 + 3) * 512];
#pragma unroll
        for (int r = 0; r < 16; ++r) {   // 16 independent FMA chains -> VALU pipe stays full
            const float4 xv = *(const float4*)&xs[(rg * 16 + r) * STR + 4 * d4];
            acc[r] = fmaf(xv.x, w0, acc[r]);
            acc[r] = fmaf(xv.y, w1, acc[r]);
            acc[r] = fmaf(xv.z, w2, acc[r]);
            acc[r] = fmaf(xv.w, w3, acc[r]);
        }
    }
#pragma unroll
    for (int r = 0; r < 16; ++r) dst[(rg * 16 + r) * STR + col] = acc[r] + bias;
}

extern "C" __global__ __launch_bounds__(512, 2)
void geat_fused(const float* __restrict__ x,
                const int* __restrict__ edges,
                const float* __restrict__ Wq, const float* __restrict__ bq,
                const float* __restrict__ Wk, const float* __restrict__ bk,
                const float* __restrict__ Wv, const float* __restrict__ bv,
                const float* __restrict__ ebias,
                const float* __restrict__ Wp, const float* __restrict__ bp,
                float* __restrict__ out)
{
    __shared__ float lds[4 * NM * STR];   // 139264 B: xs, qs, ks, vs
    float* xs = lds;
    float* qs = lds + NM * STR;           // reused as attn-out staging per head
    float* ks = lds + 2 * NM * STR;
    float* vs = lds + 3 * NM * STR;

    const int b   = blockIdx.x;
    const int tid = threadIdx.x;
    const int col = tid & 63;   // projection-phase column
    const int rg  = tid >> 6;   // projection-phase row group (== wave id)
    const int m   = tid >> 2;   // attention-phase row (wave w owns rows 16w..16w+15)
    const int q2  = tid & 3;    // attention-phase quarter: n = 4*i + q2 (bank-conflict-free)

    // ---- stage x[b] into LDS, coalesced float4 loads ----
    {
        const float4* xg = (const float4*)(x + (size_t)b * NM * ND);
#pragma unroll
        for (int t2 = 0; t2 < 4; ++t2) {
            const int fi = t2 * 512 + tid;        // float4 chunk index, 0..2047
            const float4 u = xg[fi];
            const int mm = fi >> 4;
            const int d0 = (fi & 15) * 4;
            *(float4*)&xs[mm * STR + d0] = u;
        }
    }

    float projacc[16];
#pragma unroll
    for (int r = 0; r < 16; ++r) projacc[r] = 0.f;

    const int* erow = edges + (size_t)b * NM * NM + m * NM;

    __syncthreads();

#pragma unroll 1
    for (int h = 0; h < NH; ++h) {
        // ---- QKV projections for this head ----
        proj_head(Wq + h * 64 + col, bq[h * 64 + col], xs, qs, rg, col);
        proj_head(Wk + h * 64 + col, bk[h * 64 + col], xs, ks, rg, col);
        proj_head(Wv + h * 64 + col, bv[h * 64 + col], xs, vs, rg, col);
        __syncthreads();

        // ---- load q row into registers ----
        float qa[64];
#pragma unroll
        for (int d4 = 0; d4 < 16; ++d4) {
            const float4 qv = *(const float4*)&qs[m * STR + 4 * d4];
            qa[4 * d4 + 0] = qv.x; qa[4 * d4 + 1] = qv.y;
            qa[4 * d4 + 2] = qv.z; qa[4 * d4 + 3] = qv.w;
        }

        const float eb0 = ebias[0 * NH + h];
        const float eb1 = ebias[1 * NH + h];
        const float eb2 = ebias[2 * NH + h];
        const float eb3 = ebias[3 * NH + h];
        const float eb4 = ebias[4 * NH + h];

        // ---- scores: s[m][n] = (q.k)/8 + eb[e][h], leaky relu, then mask (ref order) ----
        float p[32];
#pragma unroll
        for (int i = 0; i < 32; ++i) {
            const int n = 4 * i + q2;
            float ax = 0.f, ay = 0.f, az = 0.f, aw = 0.f;   // 4 indep chains
#pragma unroll
            for (int d4 = 0; d4 < 16; ++d4) {
                const float4 kv = *(const float4*)&ks[n * STR + 4 * d4];
                ax = fmaf(qa[4 * d4 + 0], kv.x, ax);
                ay = fmaf(qa[4 * d4 + 1], kv.y, ay);
                az = fmaf(qa[4 * d4 + 2], kv.z, az);
                aw = fmaf(qa[4 * d4 + 3], kv.w, aw);
            }
            float s = ((ax + ay) + (az + aw)) * 0.125f;
            const int e = erow[n];
            const float bias = (e == 1) ? eb1 : (e == 2) ? eb2 :
                               (e == 3) ? eb3 : (e == 4) ? eb4 : eb0;
            s += bias;
            s = (s > 0.f) ? s : 0.2f * s;          // leaky relu BEFORE mask
            p[i] = (e > 0) ? s : -1e9f;
        }

        // ---- softmax across the 4 lanes that share row m ----
        float mx = -3e38f;
#pragma unroll
        for (int i = 0; i < 32; ++i) mx = fmaxf(mx, p[i]);
        mx = fmaxf(mx, __shfl_xor(mx, 1));
        mx = fmaxf(mx, __shfl_xor(mx, 2));
        float sum = 0.f;
#pragma unroll
        for (int i = 0; i < 32; ++i) { p[i] = __expf(p[i] - mx); sum += p[i]; }
        sum += __shfl_xor(sum, 1);
        sum += __shfl_xor(sum, 2);
        const float inv = 1.f / sum;

        // ---- PV: reuse qa as accumulator ----
#pragma unroll
        for (int d = 0; d < 64; ++d) qa[d] = 0.f;
#pragma unroll
        for (int i = 0; i < 32; ++i) {
            const int n = 4 * i + q2;
            const float pw = p[i] * inv;
#pragma unroll
            for (int d4 = 0; d4 < 16; ++d4) {
                const float4 vv = *(const float4*)&vs[n * STR + 4 * d4];
                qa[4 * d4 + 0] = fmaf(pw, vv.x, qa[4 * d4 + 0]);
                qa[4 * d4 + 1] = fmaf(pw, vv.y, qa[4 * d4 + 1]);
                qa[4 * d4 + 2] = fmaf(pw, vv.z, qa[4 * d4 + 2]);
                qa[4 * d4 + 3] = fmaf(pw, vv.w, qa[4 * d4 + 3]);
            }
        }

        // ---- combine the 4 partials per row, stage attn-out row into qs ----
#pragma unroll
        for (int d = 0; d < 64; ++d) {
            float v = qa[d];
            v += __shfl_xor(v, 1);
            v += __shfl_xor(v, 2);
            if ((d >> 4) == q2) qs[m * STR + d] = v;   // each lane writes its 16-d slice
        }
        __syncthreads();

        // ---- output projection accumulate: projacc[r] += os[row][:] @ Wp[h*64+:, col] ----
        {
            const float* Wg = Wp + (h * 64) * 64 + col;
#pragma unroll
            for (int j4 = 0; j4 < 16; ++j4) {
                const float w0 = Wg[(4 * j4 + 0) * 64];
                const float w1 = Wg[(4 * j4 + 1) * 64];
                const float w2 = Wg[(4 * j4 + 2) * 64];
                const float w3 = Wg[(4 * j4 + 3) * 64];
#pragma unroll
                for (int r = 0; r < 16; ++r) {
                    const float4 ov = *(const float4*)&qs[(rg * 16 + r) * STR + 4 * j4];
                    projacc[r] = fmaf(ov.x, w0, projacc[r]);
                    projacc[r] = fmaf(ov.y, w1, projacc[r]);
                    projacc[r] = fmaf(ov.z, w2, projacc[r]);
                    projacc[r] = fmaf(ov.w, w3, projacc[r]);
                }
            }
        }
        __syncthreads();   // before next head overwrites qs/ks/vs
    }

    // ---- epilogue: add bp, coalesced f32 store ----
    {
        const float bias = bp[col];
        float* og = out + (size_t)b * NM * ND;
#pragma unroll
        for (int r = 0; r < 16; ++r) {
            og[(rg * 16 + r) * ND + col] = projacc[r] + bias;
        }
    }
}

extern "C" void kernel_launch(void* const* d_in, const int* in_sizes, int n_in,
                              void* d_out, int out_size, void* d_ws, size_t ws_size,
                              hipStream_t stream) {
    const float* x     = (const float*)d_in[0];
    const int*   edges = (const int*)d_in[1];
    const float* Wq    = (const float*)d_in[2];
    const float* bq    = (const float*)d_in[3];
    const float* Wk    = (const float*)d_in[4];
    const float* bk    = (const float*)d_in[5];
    const float* Wv    = (const float*)d_in[6];
    const float* bv    = (const float*)d_in[7];
    const float* eb    = (const float*)d_in[8];
    const float* Wp    = (const float*)d_in[9];
    const float* bp    = (const float*)d_in[10];
    float* out = (float*)d_out;

    hipLaunchKernelGGL(geat_fused, dim3(NB), dim3(512), 0, stream,
                       x, edges, Wq, bq, Wk, bk, Wv, bv, eb, Wp, bp, out);
}

// Round 3
// 12979.417 us; speedup vs baseline: 1.0040x; 1.0040x over previous
//
#include <hip/hip_runtime.h>

#define NB 256
#define NM 128
#define ND 64
#define NH 8
#define STR 68   // f32 row stride for 64-wide LDS tiles (float4-aligned, breaks pow2 bank strides)

// One head's projection: dst[m][col] = sum_d xs[m][d] * W[d][h*64+col] + bias
// Partition: col = tid&63, rg = tid>>6 owns rows rg*16..rg*16+15.
// xs reads are wave-uniform (broadcast, conflict-free); W reads coalesced (64x4B).
__device__ __forceinline__ void proj_head(const float* __restrict__ Wg, float bias,
                                          const float* __restrict__ xs,
                                          float* __restrict__ dst, int rg, int col)
{
    float acc[16];
#pragma unroll
    for (int r = 0; r < 16; ++r) acc[r] = 0.f;
#pragma unroll
    for (int d4 = 0; d4 < 16; ++d4) {
        const float w0 = Wg[(4 * d4 + 0) * 512];
        const float w1 = Wg[(4 * d4 + 1) * 512];
        const float w2 = Wg[(4 * d4 + 2) * 512];
        const float w3 = Wg[(4 * d4 + 3) * 512];
#pragma unroll
        for (int r = 0; r < 16; ++r) {   // 16 independent FMA chains -> VALU pipe stays full
            const float4 xv = *(const float4*)&xs[(rg * 16 + r) * STR + 4 * d4];
            acc[r] = fmaf(xv.x, w0, acc[r]);
            acc[r] = fmaf(xv.y, w1, acc[r]);
            acc[r] = fmaf(xv.z, w2, acc[r]);
            acc[r] = fmaf(xv.w, w3, acc[r]);
        }
    }
#pragma unroll
    for (int r = 0; r < 16; ++r) dst[(rg * 16 + r) * STR + col] = acc[r] + bias;
}

// LDS (139 KB) caps occupancy at 1 block/CU anyway -> allow full 256-VGPR budget.
// (512,2) forced a 128-VGPR cap and spilled ~50 regs/thread to scratch: 35 GB HBM
// traffic/dispatch, VALUBusy 2%. Do NOT tighten this.
extern "C" __global__ __launch_bounds__(512, 1)
void geat_fused(const float* __restrict__ x,
                const int* __restrict__ edges,
                const float* __restrict__ Wq, const float* __restrict__ bq,
                const float* __restrict__ Wk, const float* __restrict__ bk,
                const float* __restrict__ Wv, const float* __restrict__ bv,
                const float* __restrict__ ebias,
                const float* __restrict__ Wp, const float* __restrict__ bp,
                float* __restrict__ out)
{
    __shared__ float lds[4 * NM * STR];   // 139264 B: xs, qs, ks, vs
    float* xs = lds;
    float* qs = lds + NM * STR;           // reused as attn-out staging per head
    float* ks = lds + 2 * NM * STR;
    float* vs = lds + 3 * NM * STR;

    const int b   = blockIdx.x;
    const int tid = threadIdx.x;
    const int col = tid & 63;   // projection-phase column
    const int rg  = tid >> 6;   // projection-phase row group (== wave id)
    const int m   = tid >> 2;   // attention-phase row (wave w owns rows 16w..16w+15)
    const int q2  = tid & 3;    // attention-phase quarter: n = 4*i + q2 (bank-conflict-free)

    // ---- stage x[b] into LDS, coalesced float4 loads ----
    {
        const float4* xg = (const float4*)(x + (size_t)b * NM * ND);
#pragma unroll
        for (int t2 = 0; t2 < 4; ++t2) {
            const int fi = t2 * 512 + tid;        // float4 chunk index, 0..2047
            const float4 u = xg[fi];
            const int mm = fi >> 4;
            const int d0 = (fi & 15) * 4;
            *(float4*)&xs[mm * STR + d0] = u;
        }
    }

    float projacc[16];
#pragma unroll
    for (int r = 0; r < 16; ++r) projacc[r] = 0.f;

    // ---- hoist edge row (head-invariant) into registers ----
    int ecode[32];
    {
        const int* erow = edges + (size_t)b * NM * NM + m * NM;
#pragma unroll
        for (int i = 0; i < 32; ++i) ecode[i] = erow[4 * i + q2];
    }

    __syncthreads();

#pragma unroll 1
    for (int h = 0; h < NH; ++h) {
        // ---- QKV projections for this head ----
        proj_head(Wq + h * 64 + col, bq[h * 64 + col], xs, qs, rg, col);
        proj_head(Wk + h * 64 + col, bk[h * 64 + col], xs, ks, rg, col);
        proj_head(Wv + h * 64 + col, bv[h * 64 + col], xs, vs, rg, col);
        __syncthreads();

        // ---- load q row into registers ----
        float qa[64];
#pragma unroll
        for (int d4 = 0; d4 < 16; ++d4) {
            const float4 qv = *(const float4*)&qs[m * STR + 4 * d4];
            qa[4 * d4 + 0] = qv.x; qa[4 * d4 + 1] = qv.y;
            qa[4 * d4 + 2] = qv.z; qa[4 * d4 + 3] = qv.w;
        }

        const float eb0 = ebias[0 * NH + h];
        const float eb1 = ebias[1 * NH + h];
        const float eb2 = ebias[2 * NH + h];
        const float eb3 = ebias[3 * NH + h];
        const float eb4 = ebias[4 * NH + h];

        // ---- scores: s[m][n] = (q.k)/8 + eb[e][h], leaky relu, then mask (ref order) ----
        float p[32];
#pragma unroll
        for (int i = 0; i < 32; ++i) {
            const int n = 4 * i + q2;
            float ax = 0.f, ay = 0.f, az = 0.f, aw = 0.f;   // 4 indep chains
#pragma unroll
            for (int d4 = 0; d4 < 16; ++d4) {
                const float4 kv = *(const float4*)&ks[n * STR + 4 * d4];
                ax = fmaf(qa[4 * d4 + 0], kv.x, ax);
                ay = fmaf(qa[4 * d4 + 1], kv.y, ay);
                az = fmaf(qa[4 * d4 + 2], kv.z, az);
                aw = fmaf(qa[4 * d4 + 3], kv.w, aw);
            }
            float s = ((ax + ay) + (az + aw)) * 0.125f;
            const int e = ecode[i];
            const float bias = (e == 1) ? eb1 : (e == 2) ? eb2 :
                               (e == 3) ? eb3 : (e == 4) ? eb4 : eb0;
            s += bias;
            s = (s > 0.f) ? s : 0.2f * s;          // leaky relu BEFORE mask
            p[i] = (e > 0) ? s : -1e9f;
        }

        // ---- softmax across the 4 lanes that share row m ----
        float mx = -3e38f;
#pragma unroll
        for (int i = 0; i < 32; ++i) mx = fmaxf(mx, p[i]);
        mx = fmaxf(mx, __shfl_xor(mx, 1));
        mx = fmaxf(mx, __shfl_xor(mx, 2));
        float sum = 0.f;
#pragma unroll
        for (int i = 0; i < 32; ++i) { p[i] = __expf(p[i] - mx); sum += p[i]; }
        sum += __shfl_xor(sum, 1);
        sum += __shfl_xor(sum, 2);
        const float inv = 1.f / sum;

        // ---- PV: reuse qa as accumulator ----
#pragma unroll
        for (int d = 0; d < 64; ++d) qa[d] = 0.f;
#pragma unroll
        for (int i = 0; i < 32; ++i) {
            const int n = 4 * i + q2;
            const float pw = p[i] * inv;
#pragma unroll
            for (int d4 = 0; d4 < 16; ++d4) {
                const float4 vv = *(const float4*)&vs[n * STR + 4 * d4];
                qa[4 * d4 + 0] = fmaf(pw, vv.x, qa[4 * d4 + 0]);
                qa[4 * d4 + 1] = fmaf(pw, vv.y, qa[4 * d4 + 1]);
                qa[4 * d4 + 2] = fmaf(pw, vv.z, qa[4 * d4 + 2]);
                qa[4 * d4 + 3] = fmaf(pw, vv.w, qa[4 * d4 + 3]);
            }
        }

        // ---- combine the 4 partials per row, stage attn-out row into qs ----
#pragma unroll
        for (int d = 0; d < 64; ++d) {
            float v = qa[d];
            v += __shfl_xor(v, 1);
            v += __shfl_xor(v, 2);
            if ((d >> 4) == q2) qs[m * STR + d] = v;   // each lane writes its 16-d slice
        }
        __syncthreads();

        // ---- output projection accumulate: projacc[r] += os[row][:] @ Wp[h*64+:, col] ----
        {
            const float* Wg = Wp + (h * 64) * 64 + col;
#pragma unroll
            for (int j4 = 0; j4 < 16; ++j4) {
                const float w0 = Wg[(4 * j4 + 0) * 64];
                const float w1 = Wg[(4 * j4 + 1) * 64];
                const float w2 = Wg[(4 * j4 + 2) * 64];
                const float w3 = Wg[(4 * j4 + 3) * 64];
#pragma unroll
                for (int r = 0; r < 16; ++r) {
                    const float4 ov = *(const float4*)&qs[(rg * 16 + r) * STR + 4 * j4];
                    projacc[r] = fmaf(ov.x, w0, projacc[r]);
                    projacc[r] = fmaf(ov.y, w1, projacc[r]);
                    projacc[r] = fmaf(ov.z, w2, projacc[r]);
                    projacc[r] = fmaf(ov.w, w3, projacc[r]);
                }
            }
        }
        __syncthreads();   // before next head overwrites qs/ks/vs
    }

    // ---- epilogue: add bp, coalesced f32 store ----
    {
        const float bias = bp[col];
        float* og = out + (size_t)b * NM * ND;
#pragma unroll
        for (int r = 0; r < 16; ++r) {
            og[(rg * 16 + r) * ND + col] = projacc[r] + bias;
        }
    }
}

extern "C" void kernel_launch(void* const* d_in, const int* in_sizes, int n_in,
                              void* d_out, int out_size, void* d_ws, size_t ws_size,
                              hipStream_t stream) {
    const float* x     = (const float*)d_in[0];
    const int*   edges = (const int*)d_in[1];
    const float* Wq    = (const float*)d_in[2];
    const float* bq    = (const float*)d_in[3];
    const float* Wk    = (const float*)d_in[4];
    const float* bk    = (const float*)d_in[5];
    const float* Wv    = (const float*)d_in[6];
    const float* bv    = (const float*)d_in[7];
    const float* eb    = (const float*)d_in[8];
    const float* Wp    = (const float*)d_in[9];
    const float* bp    = (const float*)d_in[10];
    float* out = (float*)d_out;

    hipLaunchKernelGGL(geat_fused, dim3(NB), dim3(512), 0, stream,
                       x, edges, Wq, bq, Wk, bk, Wv, bv, eb, Wp, bp, out);
}

// Round 4
// 136.811 us; speedup vs baseline: 95.2495x; 94.8709x over previous
//
#include <hip/hip_runtime.h>

#define NB 256
#define NM 128
#define ND 64
#define NH 8

typedef float f32x4 __attribute__((ext_vector_type(4)));
typedef short bf16x8 __attribute__((ext_vector_type(8)));   // 8 bf16 = 4 VGPRs (guide §3, m89-verified)
typedef unsigned short ushort_t;

__device__ __forceinline__ ushort_t f2bf(float f) {   // RNE f32->bf16
    unsigned int x = __float_as_uint(f);
    x += 0x7fffu + ((x >> 16) & 1u);
    return (ushort_t)(x >> 16);
}

// XOR-swizzled LDS indices (T2): col ^= 8*(row&7). Applied on BOTH write and read.
// Fragment reads are 8-elem-aligned chunks, so the XOR permutes chunks cleanly.
__device__ __forceinline__ int sw64(int row, int col)  { return row * 64  + (col ^ ((row & 7) << 3)); }
__device__ __forceinline__ int sw128(int row, int col) { return row * 128 + (col ^ ((row & 7) << 3)); }

__device__ __forceinline__ f32x4 MFMA(bf16x8 a, bf16x8 b, f32x4 c) {
    return __builtin_amdgcn_mfma_f32_16x16x32_bf16(a, b, c, 0, 0, 0);
}

// ---- prep: transpose weights to bf16 fragment-friendly layout in d_ws ----
// ws (ushort): WqT[512][64] @0, WkT @32768, WvT @65536, WpT[64][512] @98304  (256 KB)
extern "C" __global__ void geat_prep(const float* __restrict__ Wq,
                                     const float* __restrict__ Wk,
                                     const float* __restrict__ Wv,
                                     const float* __restrict__ Wp,
                                     ushort_t* __restrict__ ws)
{
    int idx = blockIdx.x * 256 + threadIdx.x;   // 0..131071
    int seg = idx >> 15;
    int r = idx & 32767;
    float v;
    if      (seg == 0) v = Wq[(r & 63) * 512 + (r >> 6)];    // WqT[o][d] = Wq[d][o]
    else if (seg == 1) v = Wk[(r & 63) * 512 + (r >> 6)];
    else if (seg == 2) v = Wv[(r & 63) * 512 + (r >> 6)];
    else               v = Wp[(r & 511) * 64 + (r >> 9)];    // WpT[c][k] = Wp[k][c]
    ws[idx] = f2bf(v);
}

extern "C" __global__ __launch_bounds__(512, 1)
void geat_mfma(const float* __restrict__ x, const int* __restrict__ edges,
               const float* __restrict__ bq, const float* __restrict__ bk,
               const float* __restrict__ bv, const float* __restrict__ ebias,
               const float* __restrict__ bp, const ushort_t* __restrict__ wt,
               float* __restrict__ out)
{
    __shared__ __align__(16) ushort_t sm[49152];   // 96 KB bf16: XB,QB,KB,VT,PB
    ushort_t* XB  = sm;                 // x    [128][64]
    ushort_t* QB  = sm + 8192;          // Q    [128][64] (reused for O tiles)
    ushort_t* KB  = sm + 16384;         // K    [128][64]
    ushort_t* VTB = sm + 24576;         // V^T  [64][128]
    ushort_t* PB  = sm + 32768;         // P    [128][128]

    const int b    = blockIdx.x;
    const int tid  = threadIdx.x;
    const int w    = tid >> 6;          // wave 0..7
    const int lane = tid & 63;
    const int c    = lane & 15;         // fragment row/col index
    const int g    = lane >> 4;         // k-chunk group 0..3
    const int mt   = w * 16;            // wave's output rows

    const ushort_t* WqT = wt;
    const ushort_t* WkT = wt + 32768;
    const ushort_t* WvT = wt + 65536;
    const ushort_t* WpT = wt + 98304;

    // ---- stage x -> XB (bf16, swizzled), coalesced float4 reads ----
    {
        const float4* xg = (const float4*)(x + (size_t)b * NM * ND);
#pragma unroll
        for (int rep = 0; rep < 4; ++rep) {
            int fi = rep * 512 + tid;            // 0..2047
            float4 v = xg[fi];
            int m  = fi >> 4;
            int k0 = (fi & 15) * 4;
            uint2 pk;
            pk.x = (unsigned)f2bf(v.x) | ((unsigned)f2bf(v.y) << 16);
            pk.y = (unsigned)f2bf(v.z) | ((unsigned)f2bf(v.w) << 16);
            *(uint2*)&XB[sw64(m, k0)] = pk;      // k0%4==0, xor mult-of-8 keeps alignment
        }
    }

    // ---- cache edge codes for this wave's S fragments (head-invariant) ----
    // element (m = mt+4g+r, n = nt*16+c); values 0..4 packed 4x8b per nt
    unsigned epack[8];
    {
        const int* eg = edges + (size_t)b * NM * NM;
#pragma unroll
        for (int nt = 0; nt < 8; ++nt) {
            unsigned pk = 0;
#pragma unroll
            for (int r = 0; r < 4; ++r)
                pk |= ((unsigned)eg[(mt + 4 * g + r) * NM + nt * 16 + c] & 0xffu) << (8 * r);
            epack[nt] = pk;
        }
    }

    f32x4 projacc[4];
#pragma unroll
    for (int i = 0; i < 4; ++i) projacc[i] = (f32x4)0.0f;

    __syncthreads();

#pragma unroll 1
    for (int h = 0; h < NH; ++h) {
        // ================= Phase A: Q, K, V^T projections =================
        // x A-frags for rows mt+c; ALSO the x^T B-frags for V^T (n'0 = mt) — same data.
        bf16x8 xA[2];
#pragma unroll
        for (int kt = 0; kt < 2; ++kt)
            xA[kt] = *(const bf16x8*)&XB[sw64(mt + c, kt * 32 + 8 * g)];

        // Q, K: wave computes its 16 rows, all 4 col-tiles
#pragma unroll
        for (int nt4 = 0; nt4 < 4; ++nt4) {
            int n0 = nt4 * 16;
            float bqv = bq[h * 64 + n0 + c];
            float bkv = bk[h * 64 + n0 + c];
            f32x4 qacc = {bqv, bqv, bqv, bqv};   // bias depends on col only
            f32x4 kacc = {bkv, bkv, bkv, bkv};
#pragma unroll
            for (int kt = 0; kt < 2; ++kt) {
                const bf16x8 wq = *(const bf16x8*)&WqT[(h * 64 + n0 + c) * 64 + kt * 32 + 8 * g];
                const bf16x8 wk = *(const bf16x8*)&WkT[(h * 64 + n0 + c) * 64 + kt * 32 + 8 * g];
                qacc = MFMA(xA[kt], wq, qacc);
                kacc = MFMA(xA[kt], wk, kacc);
            }
#pragma unroll
            for (int r = 0; r < 4; ++r) {        // D-frag: row=mt+4g+r, col=n0+c
                QB[sw64(mt + 4 * g + r, n0 + c)] = f2bf(qacc[r]);
                KB[sw64(mt + 4 * g + r, n0 + c)] = f2bf(kacc[r]);
            }
        }
        // V^T = WvT · x^T : wave w computes V^T cols mt..mt+15, all 64 d-rows
#pragma unroll
        for (int dt = 0; dt < 4; ++dt) {
            int d0 = dt * 16;
            f32x4 vacc;
#pragma unroll
            for (int r = 0; r < 4; ++r) vacc[r] = bv[h * 64 + d0 + 4 * g + r];  // bias on d (row)
#pragma unroll
            for (int kt = 0; kt < 2; ++kt) {
                const bf16x8 wv = *(const bf16x8*)&WvT[(h * 64 + d0 + c) * 64 + kt * 32 + 8 * g];
                vacc = MFMA(wv, xA[kt], vacc);   // A = WvT rows (d), B = x^T cols (n=mt+c)
            }
#pragma unroll
            for (int r = 0; r < 4; ++r)
                VTB[sw128(d0 + 4 * g + r, mt + c)] = f2bf(vacc[r]);
        }
        __syncthreads();   // barrier 1: KB / VTB shared across waves

        // ================= Phase B: S = QK^T/8 + bias, leaky, mask, softmax, P =================
        bf16x8 qA[2];
#pragma unroll
        for (int kt = 0; kt < 2; ++kt)
            qA[kt] = *(const bf16x8*)&QB[sw64(mt + c, kt * 32 + 8 * g)];

        float eb0 = ebias[0 * NH + h], eb1 = ebias[1 * NH + h], eb2 = ebias[2 * NH + h];
        float eb3 = ebias[3 * NH + h], eb4 = ebias[4 * NH + h];

        f32x4 s[8];
#pragma unroll
        for (int nt = 0; nt < 8; ++nt) {
            int n0 = nt * 16;
            f32x4 acc = (f32x4)0.0f;
#pragma unroll
            for (int kt = 0; kt < 2; ++kt) {
                const bf16x8 kf = *(const bf16x8*)&KB[sw64(n0 + c, kt * 32 + 8 * g)];
                acc = MFMA(qA[kt], kf, acc);
            }
#pragma unroll
            for (int r = 0; r < 4; ++r) {
                int e = (epack[nt] >> (8 * r)) & 0xff;
                float bias = (e == 1) ? eb1 : (e == 2) ? eb2 : (e == 3) ? eb3 : (e == 4) ? eb4 : eb0;
                float sv = acc[r] * 0.125f + bias;
                sv = (sv > 0.f) ? sv : 0.2f * sv;        // leaky BEFORE mask (ref order)
                acc[r] = (e > 0) ? sv : -1e9f;
            }
            s[nt] = acc;
        }
        // softmax per row (row = mt+4g+r): per-lane partial over nt, then 16-lane butterfly
        f32x4 mx;
#pragma unroll
        for (int r = 0; r < 4; ++r) {
            float m0 = s[0][r];
#pragma unroll
            for (int nt = 1; nt < 8; ++nt) m0 = fmaxf(m0, s[nt][r]);
            mx[r] = m0;
        }
#pragma unroll
        for (int d = 1; d < 16; d <<= 1)
#pragma unroll
            for (int r = 0; r < 4; ++r) mx[r] = fmaxf(mx[r], __shfl_xor(mx[r], d));
        f32x4 sum = (f32x4)0.0f;
#pragma unroll
        for (int nt = 0; nt < 8; ++nt)
#pragma unroll
            for (int r = 0; r < 4; ++r) {
                float ev = __expf(s[nt][r] - mx[r]);
                s[nt][r] = ev;
                sum[r] += ev;
            }
#pragma unroll
        for (int d = 1; d < 16; d <<= 1)
#pragma unroll
            for (int r = 0; r < 4; ++r) sum[r] += __shfl_xor(sum[r], d);
        f32x4 inv;
#pragma unroll
        for (int r = 0; r < 4; ++r) inv[r] = 1.f / sum[r];
#pragma unroll
        for (int nt = 0; nt < 8; ++nt)
#pragma unroll
            for (int r = 0; r < 4; ++r)
                PB[sw128(mt + 4 * g + r, nt * 16 + c)] = f2bf(s[nt][r] * inv[r]);
        // P rows are wave-private (written & read only by wave w) -> no barrier

        // ================= Phase C: O = P·V, then out-proj accumulate =================
        bf16x8 pA[4];
#pragma unroll
        for (int kt = 0; kt < 4; ++kt)
            pA[kt] = *(const bf16x8*)&PB[sw128(mt + c, kt * 32 + 8 * g)];
#pragma unroll
        for (int dt = 0; dt < 4; ++dt) {
            int d0 = dt * 16;
            f32x4 oacc = (f32x4)0.0f;
#pragma unroll
            for (int kt = 0; kt < 4; ++kt) {
                const bf16x8 vf = *(const bf16x8*)&VTB[sw128(d0 + c, kt * 32 + 8 * g)];
                oacc = MFMA(pA[kt], vf, oacc);   // B-frag: V[k][d0+c] = VT[d0+c][k]
            }
#pragma unroll
            for (int r = 0; r < 4; ++r)          // O tile -> QB own rows (Q is dead)
                QB[sw64(mt + 4 * g + r, d0 + c)] = f2bf(oacc[r]);
        }
        bf16x8 oA[2];
#pragma unroll
        for (int kt = 0; kt < 2; ++kt)
            oA[kt] = *(const bf16x8*)&QB[sw64(mt + c, kt * 32 + 8 * g)];
#pragma unroll
        for (int nt4 = 0; nt4 < 4; ++nt4) {
            int n0 = nt4 * 16;
#pragma unroll
            for (int kt = 0; kt < 2; ++kt) {
                const bf16x8 wp = *(const bf16x8*)&WpT[(n0 + c) * 512 + h * 64 + kt * 32 + 8 * g];
                projacc[nt4] = MFMA(oA[kt], wp, projacc[nt4]);
            }
        }
        __syncthreads();   // barrier 2: before next head overwrites KB/VTB/PB
    }

    // ---- epilogue: + bp, coalesced f32 stores ----
    {
        float* og = out + (size_t)b * NM * ND;
#pragma unroll
        for (int nt4 = 0; nt4 < 4; ++nt4) {
            int n0 = nt4 * 16;
            float bpv = bp[n0 + c];
#pragma unroll
            for (int r = 0; r < 4; ++r)
                og[(mt + 4 * g + r) * ND + n0 + c] = projacc[nt4][r] + bpv;
        }
    }
}

extern "C" void kernel_launch(void* const* d_in, const int* in_sizes, int n_in,
                              void* d_out, int out_size, void* d_ws, size_t ws_size,
                              hipStream_t stream) {
    const float* x     = (const float*)d_in[0];
    const int*   edges = (const int*)d_in[1];
    const float* Wq    = (const float*)d_in[2];
    const float* bq    = (const float*)d_in[3];
    const float* Wk    = (const float*)d_in[4];
    const float* bk    = (const float*)d_in[5];
    const float* Wv    = (const float*)d_in[6];
    const float* bv    = (const float*)d_in[7];
    const float* eb    = (const float*)d_in[8];
    const float* Wp    = (const float*)d_in[9];
    const float* bp    = (const float*)d_in[10];
    float* out = (float*)d_out;
    ushort_t* ws = (ushort_t*)d_ws;   // needs 262144 B

    hipLaunchKernelGGL(geat_prep, dim3(512), dim3(256), 0, stream, Wq, Wk, Wv, Wp, ws);
    hipLaunchKernelGGL(geat_mfma, dim3(NB), dim3(512), 0, stream,
                       x, edges, bq, bk, bv, eb, bp, ws, out);
}